// Round 6
// baseline (117.099 us; speedup 1.0000x reference)
//
#include <hip/hip_runtime.h>
#include <hip/hip_cooperative_groups.h>
#include <math.h>

namespace cg = cooperative_groups;

#define PCNT 1024
#define HH 160
#define WW 160
#define NPIX (HH * WW)
#define TILE 8
#define TX (WW / TILE)       // 20
#define TY (HH / TILE)       // 20
#define NTILES (TX * TY)     // 400

// sorted params: 3 x float4 per gaussian: {px,py,ca',cb'}, {cc',op,r,g}, {b,0,0,0}
// ca',cb',cc' pre-scaled by 0.5*log2(e) / log2(e) (power in log2 domain).
// cull table: {px,py,hx,hy} per gaussian.

__global__ __launch_bounds__(64) void k_fused(
    const float* __restrict__ means, const float* __restrict__ cols,
    const float* __restrict__ ops, const float* __restrict__ scales,
    const float* __restrict__ rots, const float* __restrict__ vm,
    const float* __restrict__ pm, float* __restrict__ radii_out,
    float4* __restrict__ params16, unsigned long long* __restrict__ keys,
    float4* __restrict__ sortedp, float4* __restrict__ cull,
    const float* __restrict__ bg, float* __restrict__ out)
{
    __shared__ unsigned short list[PCNT];   // 2 KB
    __shared__ float4 stage[64 * 3];        // 3 KB

    int bid  = blockIdx.x;
    int lane = threadIdx.x;
    cg::grid_group grid = cg::this_grid();

    // ---------------- Phase A: per-gaussian preprocess ----------------
    {
        int i = lane * NTILES + bid;        // <=3 active lanes per block
        if (i < PCNT) {
            float mx = means[3 * i], my = means[3 * i + 1], mz = means[3 * i + 2];

            float t0 = vm[0] * mx + vm[1] * my + vm[2] * mz + vm[3];
            float t1 = vm[4] * mx + vm[5] * my + vm[6] * mz + vm[7];
            float t2 = vm[8] * mx + vm[9] * my + vm[10] * mz + vm[11];
            bool depth_ok = t2 > 0.2f;

            float ph0 = pm[0] * mx + pm[1] * my + pm[2] * mz + pm[3];
            float ph1 = pm[4] * mx + pm[5] * my + pm[6] * mz + pm[7];
            float ph3 = pm[12] * mx + pm[13] * my + pm[14] * mz + pm[15];
            float pw = 1.0f / (ph3 + 1e-7f);
            float px = ((ph0 * pw + 1.0f) * (float)WW - 1.0f) * 0.5f;
            float py = ((ph1 * pw + 1.0f) * (float)HH - 1.0f) * 0.5f;

            float qr = rots[4 * i], qx = rots[4 * i + 1], qy = rots[4 * i + 2], qz = rots[4 * i + 3];
            float R00 = 1.f - 2.f * (qy * qy + qz * qz), R01 = 2.f * (qx * qy - qr * qz), R02 = 2.f * (qx * qz + qr * qy);
            float R10 = 2.f * (qx * qy + qr * qz), R11 = 1.f - 2.f * (qx * qx + qz * qz), R12 = 2.f * (qy * qz - qr * qx);
            float R20 = 2.f * (qx * qz - qr * qy), R21 = 2.f * (qy * qz + qr * qx), R22 = 1.f - 2.f * (qx * qx + qy * qy);

            float s0 = scales[3 * i], s1 = scales[3 * i + 1], s2 = scales[3 * i + 2];
            float M00 = R00 * s0, M01 = R01 * s1, M02 = R02 * s2;
            float M10 = R10 * s0, M11 = R11 * s1, M12 = R12 * s2;
            float M20 = R20 * s0, M21 = R21 * s1, M22 = R22 * s2;
            float c00 = M00 * M00 + M01 * M01 + M02 * M02;
            float c01 = M00 * M10 + M01 * M11 + M02 * M12;
            float c02 = M00 * M20 + M01 * M21 + M02 * M22;
            float c11 = M10 * M10 + M11 * M11 + M12 * M12;
            float c12 = M10 * M20 + M11 * M21 + M12 * M22;
            float c22 = M20 * M20 + M21 * M21 + M22 * M22;

            const float fx = 160.0f, fy = 160.0f;
            const float limx = 0.65f, limy = 0.65f;
            float txz = fminf(limx, fmaxf(-limx, t0 / t2)) * t2;
            float tyz = fminf(limy, fmaxf(-limy, t1 / t2)) * t2;
            float J00 = fx / t2, J02 = -fx * txz / (t2 * t2);
            float J11 = fy / t2, J12 = -fy * tyz / (t2 * t2);

            float T00 = J00 * vm[0] + J02 * vm[8];
            float T01 = J00 * vm[1] + J02 * vm[9];
            float T02 = J00 * vm[2] + J02 * vm[10];
            float T10 = J11 * vm[4] + J12 * vm[8];
            float T11 = J11 * vm[5] + J12 * vm[9];
            float T12 = J11 * vm[6] + J12 * vm[10];

            float u00 = T00 * c00 + T01 * c01 + T02 * c02;
            float u01 = T00 * c01 + T01 * c11 + T02 * c12;
            float u02 = T00 * c02 + T01 * c12 + T02 * c22;
            float u10 = T10 * c00 + T11 * c01 + T12 * c02;
            float u11 = T10 * c01 + T11 * c11 + T12 * c12;
            float u12 = T10 * c02 + T11 * c12 + T12 * c22;
            float a  = u00 * T00 + u01 * T01 + u02 * T02 + 0.3f;
            float bb = u00 * T10 + u01 * T11 + u02 * T12;
            float cc = u10 * T10 + u11 * T11 + u12 * T12 + 0.3f;

            float det = a * cc - bb * bb;
            bool det_ok = det > 0.0f;
            float inv_det = det_ok ? 1.0f / det : 0.0f;
            float conA = cc * inv_det, conB = -bb * inv_det, conC = a * inv_det;
            float mid = 0.5f * (a + cc);
            float lam1 = mid + sqrtf(fmaxf(0.1f, mid * mid - det));
            float radius = ceilf(3.0f * sqrtf(lam1));
            bool valid = depth_ok && det_ok;

            radii_out[i] = valid ? (float)(int)radius : 0.0f;

            const float HL2E = 0.72134752044448170f;  // 0.5*log2(e)
            const float L2E  = 1.4426950408889634f;   // log2(e)

            float4 v0, v1, v2, v3;
            if (valid) {
                float op = ops[i];
                float tau = fmaxf(logf(255.0f * op) + 0.02f, 0.0f);
                float hx = sqrtf(2.0f * tau * a);
                float hy = sqrtf(2.0f * tau * cc);
                v0 = make_float4(px, py, conA * HL2E, conB * L2E);
                v1 = make_float4(conC * HL2E, op, cols[3 * i], cols[3 * i + 1]);
                v2 = make_float4(cols[3 * i + 2], 0.f, 0.f, 0.f);
                v3 = make_float4(px, py, hx, hy);
            } else {
                v0 = make_float4(0.f, 0.f, 0.f, 0.f);
                v1 = v0; v2 = v0;
                v3 = make_float4(0.f, 0.f, -1e9f, -1e9f);
            }
            params16[i * 4 + 0] = v0;
            params16[i * 4 + 1] = v1;
            params16[i * 4 + 2] = v2;
            params16[i * 4 + 3] = v3;

            unsigned int kb = valid ? __float_as_uint(t2) : 0x7f800000u;
            keys[i] = ((unsigned long long)kb << 32) | (unsigned int)i;
        }
    }

    grid.sync();

    // ---------------- Phase B: rank-by-count + scatter ----------------
    for (int g = bid; g < PCNT; g += NTILES) {
        unsigned long long mykey = keys[g];
        const unsigned long long* kp = keys + lane * 16;
        int cnt = 0;
        #pragma unroll
        for (int k = 0; k < 16; ++k)
            cnt += (kp[k] < mykey) ? 1 : 0;
        cnt += __shfl_xor(cnt, 1);
        cnt += __shfl_xor(cnt, 2);
        cnt += __shfl_xor(cnt, 4);
        cnt += __shfl_xor(cnt, 8);
        cnt += __shfl_xor(cnt, 16);
        cnt += __shfl_xor(cnt, 32);
        // all lanes now hold rank(g)
        if (lane < 3)       sortedp[cnt * 3 + lane] = params16[g * 4 + lane];
        else if (lane == 3) cull[cnt]               = params16[g * 4 + 3];
    }

    grid.sync();

    // ---------------- Phase C: per-tile cull + composite ----------------
    int tx = bid % TX, ty = bid / TX;
    float x0 = (float)(tx * TILE), y0 = (float)(ty * TILE);

    int n = 0;
    #pragma unroll 4
    for (int k = 0; k < PCNT / 64; ++k) {
        float4 cv = cull[k * 64 + lane];    // px,py,hx,hy (depth-sorted)
        bool ov = (cv.x + cv.z >= x0 - 1.0f) & (cv.x - cv.z <= x0 + (float)TILE) &
                  (cv.y + cv.w >= y0 - 1.0f) & (cv.y - cv.w <= y0 + (float)TILE);
        unsigned long long mask = __ballot(ov);
        if (ov) list[n + __popcll(mask & ((1ull << lane) - 1ull))] =
                    (unsigned short)(k * 64 + lane);
        n += __popcll(mask);
    }

    float fxp = x0 + (float)(lane & 7);
    float fyp = y0 + (float)(lane >> 3);

    float T = 1.0f, C0 = 0.f, C1 = 0.f, C2 = 0.f;
    for (int base = 0; base < n; base += 64) {
        int m = min(64, n - base);
        __syncthreads();
        if (lane < m) {
            int idx = list[base + lane];
            stage[lane * 3 + 0] = sortedp[idx * 3 + 0];
            stage[lane * 3 + 1] = sortedp[idx * 3 + 1];
            stage[lane * 3 + 2] = sortedp[idx * 3 + 2];
        }
        __syncthreads();
        #pragma unroll 4
        for (int i = 0; i < m; ++i) {
            float4 v0 = stage[3 * i + 0];   // px,py,ca',cb'
            float4 v1 = stage[3 * i + 1];   // cc',op,r,g
            float4 v2 = stage[3 * i + 2];   // b,-,-,-
            float dx = v0.x - fxp, dy = v0.y - fyp;
            float p = -(v0.z * dx * dx + v1.x * dy * dy) - v0.w * dx * dy;
            float e; asm("v_exp_f32 %0, %1" : "=v"(e) : "v"(p));
            float al = fminf(0.99f, v1.y * e);
            if (p > 0.0f || al < (1.0f / 255.0f)) al = 0.0f;
            float w = al * T;
            C0 = fmaf(w, v1.z, C0);
            C1 = fmaf(w, v1.w, C1);
            C2 = fmaf(w, v2.x, C2);
            T *= (1.0f - al);
        }
    }

    int pix = ((int)fyp) * WW + (int)fxp;
    out[pix]            = C0 + T * bg[0];
    out[NPIX + pix]     = C1 + T * bg[1];
    out[2 * NPIX + pix] = C2 + T * bg[2];
}

extern "C" void kernel_launch(void* const* d_in, const int* in_sizes, int n_in,
                              void* d_out, int out_size, void* d_ws, size_t ws_size,
                              hipStream_t stream) {
    const float* means  = (const float*)d_in[0];
    const float* cols   = (const float*)d_in[2];
    const float* ops    = (const float*)d_in[3];
    const float* scales = (const float*)d_in[4];
    const float* rots   = (const float*)d_in[5];
    const float* bg     = (const float*)d_in[6];
    const float* vm     = (const float*)d_in[7];
    const float* pm     = (const float*)d_in[8];

    float* out   = (float*)d_out;            // [3*NPIX color][PCNT radii-as-float]
    float* radii = out + 3 * NPIX;

    float4* params16 = (float4*)d_ws;                                   // PCNT*64B
    float4* sortedp  = params16 + PCNT * 4;                             // PCNT*48B
    float4* cullt    = sortedp + PCNT * 3;                              // PCNT*16B
    unsigned long long* keys = (unsigned long long*)(cullt + PCNT);     // PCNT*8B

    void* args[] = {
        (void*)&means, (void*)&cols, (void*)&ops, (void*)&scales, (void*)&rots,
        (void*)&vm, (void*)&pm, (void*)&radii, (void*)&params16, (void*)&keys,
        (void*)&sortedp, (void*)&cullt, (void*)&bg, (void*)&out
    };
    hipLaunchCooperativeKernel((void*)k_fused, dim3(NTILES), dim3(64),
                               args, 0, stream);
}

// Round 7
// 22.926 us; speedup vs baseline: 5.1078x; 5.1078x over previous
//
#include <hip/hip_runtime.h>
#include <math.h>

#define PCNT 1024
#define HH 160
#define WW 160
#define NPIX (HH * WW)
#define TILE 8
#define TX (WW / TILE)       // 20
#define TY (HH / TILE)       // 20
#define NTILES (TX * TY)     // 400

// One block = one 8x8 tile. The block recomputes preprocess for ALL gaussians
// into LDS (redundant across blocks, but removes every cross-block dependency:
// single dispatch, no grid sync, no global scratch).
__global__ __launch_bounds__(256) void k_all(
    const float* __restrict__ means, const float* __restrict__ cols,
    const float* __restrict__ ops, const float* __restrict__ scales,
    const float* __restrict__ rots, const float* __restrict__ vm,
    const float* __restrict__ pm, const float* __restrict__ bg,
    float* __restrict__ out)
{
    __shared__ float4 sp[PCNT * 3];           // 48 KB params {px,py,ca',cb'},{cc',op,r,g},{b,-,-,-}
    __shared__ float4 cl[PCNT];               // 16 KB cull {px,py,hx,hy}; reused as part[] later
    __shared__ unsigned int kbits[PCNT];      // 4 KB depth key bits
    __shared__ unsigned long long sl[PCNT];   // 8 KB per-tile sorted list
    __shared__ int sn;

    int tid = threadIdx.x;
    int bid = blockIdx.x;
    int wave = tid >> 6, lane = tid & 63;

    const float HL2E = 0.72134752044448170f;  // 0.5*log2(e)
    const float L2E  = 1.4426950408889634f;   // log2(e)

    // ---------------- Phase A: preprocess all gaussians into LDS ----------------
    for (int i = tid; i < PCNT; i += 256) {
        float mx = means[3 * i], my = means[3 * i + 1], mz = means[3 * i + 2];

        float t0 = vm[0] * mx + vm[1] * my + vm[2] * mz + vm[3];
        float t1 = vm[4] * mx + vm[5] * my + vm[6] * mz + vm[7];
        float t2 = vm[8] * mx + vm[9] * my + vm[10] * mz + vm[11];
        bool depth_ok = t2 > 0.2f;

        float ph0 = pm[0] * mx + pm[1] * my + pm[2] * mz + pm[3];
        float ph1 = pm[4] * mx + pm[5] * my + pm[6] * mz + pm[7];
        float ph3 = pm[12] * mx + pm[13] * my + pm[14] * mz + pm[15];
        float pw = 1.0f / (ph3 + 1e-7f);
        float px = ((ph0 * pw + 1.0f) * (float)WW - 1.0f) * 0.5f;
        float py = ((ph1 * pw + 1.0f) * (float)HH - 1.0f) * 0.5f;

        float qr = rots[4 * i], qx = rots[4 * i + 1], qy = rots[4 * i + 2], qz = rots[4 * i + 3];
        float R00 = 1.f - 2.f * (qy * qy + qz * qz), R01 = 2.f * (qx * qy - qr * qz), R02 = 2.f * (qx * qz + qr * qy);
        float R10 = 2.f * (qx * qy + qr * qz), R11 = 1.f - 2.f * (qx * qx + qz * qz), R12 = 2.f * (qy * qz - qr * qx);
        float R20 = 2.f * (qx * qz - qr * qy), R21 = 2.f * (qy * qz + qr * qx), R22 = 1.f - 2.f * (qx * qx + qy * qy);

        float s0 = scales[3 * i], s1 = scales[3 * i + 1], s2 = scales[3 * i + 2];
        float M00 = R00 * s0, M01 = R01 * s1, M02 = R02 * s2;
        float M10 = R10 * s0, M11 = R11 * s1, M12 = R12 * s2;
        float M20 = R20 * s0, M21 = R21 * s1, M22 = R22 * s2;
        float c00 = M00 * M00 + M01 * M01 + M02 * M02;
        float c01 = M00 * M10 + M01 * M11 + M02 * M12;
        float c02 = M00 * M20 + M01 * M21 + M02 * M22;
        float c11 = M10 * M10 + M11 * M11 + M12 * M12;
        float c12 = M10 * M20 + M11 * M21 + M12 * M22;
        float c22 = M20 * M20 + M21 * M21 + M22 * M22;

        const float fx = 160.0f, fy = 160.0f;
        const float limx = 0.65f, limy = 0.65f;
        float txz = fminf(limx, fmaxf(-limx, t0 / t2)) * t2;
        float tyz = fminf(limy, fmaxf(-limy, t1 / t2)) * t2;
        float J00 = fx / t2, J02 = -fx * txz / (t2 * t2);
        float J11 = fy / t2, J12 = -fy * tyz / (t2 * t2);

        float T00 = J00 * vm[0] + J02 * vm[8];
        float T01 = J00 * vm[1] + J02 * vm[9];
        float T02 = J00 * vm[2] + J02 * vm[10];
        float T10 = J11 * vm[4] + J12 * vm[8];
        float T11 = J11 * vm[5] + J12 * vm[9];
        float T12 = J11 * vm[6] + J12 * vm[10];

        float u00 = T00 * c00 + T01 * c01 + T02 * c02;
        float u01 = T00 * c01 + T01 * c11 + T02 * c12;
        float u02 = T00 * c02 + T01 * c12 + T02 * c22;
        float u10 = T10 * c00 + T11 * c01 + T12 * c02;
        float u11 = T10 * c01 + T11 * c11 + T12 * c12;
        float u12 = T10 * c02 + T11 * c12 + T12 * c22;
        float a  = u00 * T00 + u01 * T01 + u02 * T02 + 0.3f;
        float bb = u00 * T10 + u01 * T11 + u02 * T12;
        float cc = u10 * T10 + u11 * T11 + u12 * T12 + 0.3f;

        float det = a * cc - bb * bb;
        bool det_ok = det > 0.0f;
        float inv_det = det_ok ? 1.0f / det : 0.0f;
        float conA = cc * inv_det, conB = -bb * inv_det, conC = a * inv_det;
        float mid = 0.5f * (a + cc);
        float lam1 = mid + sqrtf(fmaxf(0.1f, mid * mid - det));
        float radius = ceilf(3.0f * sqrtf(lam1));
        bool valid = depth_ok && det_ok;

        if (bid == 0)
            out[3 * NPIX + i] = valid ? (float)(int)radius : 0.0f;

        if (valid) {
            float op = ops[i];
            // contribution is exactly 0 unless Q <= tau (alpha >= 1/255);
            // bounding half-widths: hx=sqrt(2*tau*a), hy=sqrt(2*tau*c) (+slop).
            float tau = fmaxf(logf(255.0f * op) + 0.02f, 0.0f);
            float hx = sqrtf(2.0f * tau * a);
            float hy = sqrtf(2.0f * tau * cc);
            sp[i * 3 + 0] = make_float4(px, py, conA * HL2E, conB * L2E);
            sp[i * 3 + 1] = make_float4(conC * HL2E, op, cols[3 * i], cols[3 * i + 1]);
            sp[i * 3 + 2] = make_float4(cols[3 * i + 2], 0.f, 0.f, 0.f);
            cl[i] = make_float4(px, py, hx, hy);
            kbits[i] = __float_as_uint(t2);
        } else {
            sp[i * 3 + 0] = make_float4(0.f, 0.f, 0.f, 0.f);
            sp[i * 3 + 1] = make_float4(0.f, 0.f, 0.f, 0.f);
            sp[i * 3 + 2] = make_float4(0.f, 0.f, 0.f, 0.f);
            cl[i] = make_float4(0.f, 0.f, -1e9f, -1e9f);  // never overlaps
            kbits[i] = 0x7f800000u;
        }
    }
    __syncthreads();

    // ---------------- Phase B: tile cull + ordered compaction (wave 0) ----------------
    int tx = bid % TX, ty = bid / TX;
    float x0 = (float)(tx * TILE), y0 = (float)(ty * TILE);

    if (wave == 0) {
        int n = 0;
        for (int k = 0; k < PCNT / 64; ++k) {
            int g = k * 64 + lane;
            float4 cv = cl[g];
            bool ov = (cv.x + cv.z >= x0 - 1.0f) & (cv.x - cv.z <= x0 + (float)TILE) &
                      (cv.y + cv.w >= y0 - 1.0f) & (cv.y - cv.w <= y0 + (float)TILE);
            unsigned long long mask = __ballot(ov);
            if (ov) sl[n + __popcll(mask & ((1ull << lane) - 1ull))] =
                        ((unsigned long long)kbits[g] << 32) | (unsigned int)g;
            n += __popcll(mask);
        }
        if (lane == 0) sn = n;
    }
    __syncthreads();
    int n = sn;

    // ---------------- Phase C: bitonic sort the per-tile list ----------------
    if (n > 1) {
        int p2 = 2; while (p2 < n) p2 <<= 1;
        for (int t = tid; t < p2; t += 256)
            if (t >= n) sl[t] = ~0ull;
        __syncthreads();
        for (int k = 2; k <= p2; k <<= 1) {
            for (int j = k >> 1; j > 0; j >>= 1) {
                for (int t = tid; t < p2; t += 256) {
                    int ixj = t ^ j;
                    if (ixj > t) {
                        unsigned long long a = sl[t], b = sl[ixj];
                        bool asc = ((t & k) == 0);
                        if (asc ? (a > b) : (a < b)) { sl[t] = b; sl[ixj] = a; }
                    }
                }
                __syncthreads();
            }
        }
    }

    // ---------------- Phase D: segmented front-to-back composite ----------------
    float fxp = x0 + (float)(lane & 7);
    float fyp = y0 + (float)(lane >> 3);

    float T = 1.0f, C0 = 0.f, C1 = 0.f, C2 = 0.f;
    int per = (n + 3) >> 2;
    int lo = wave * per, hi = min(n, lo + per);
    for (int i = lo; i < hi; ++i) {
        int id = (int)(sl[i] & 1023u);
        float4 v0 = sp[id * 3 + 0];   // px,py,ca',cb'
        float4 v1 = sp[id * 3 + 1];   // cc',op,r,g
        float4 v2 = sp[id * 3 + 2];   // b,-,-,-
        float dx = v0.x - fxp, dy = v0.y - fyp;
        float p = -(v0.z * dx * dx + v1.x * dy * dy) - v0.w * dx * dy;
        float e; asm("v_exp_f32 %0, %1" : "=v"(e) : "v"(p));
        float al = fminf(0.99f, v1.y * e);
        if (p > 0.0f || al < (1.0f / 255.0f)) al = 0.0f;
        float w = al * T;
        C0 = fmaf(w, v1.z, C0);
        C1 = fmaf(w, v1.w, C1);
        C2 = fmaf(w, v2.x, C2);
        T *= (1.0f - al);
    }

    // reuse cl[] as the partials buffer (cull data dead after Phase B)
    float4* part = cl;
    __syncthreads();
    part[wave * 64 + lane] = make_float4(C0, C1, C2, T);
    __syncthreads();

    if (tid < 64) {
        float Tt = 1.0f, c0 = 0.f, c1 = 0.f, c2 = 0.f;
        #pragma unroll
        for (int s = 0; s < 4; ++s) {
            float4 v = part[s * 64 + tid];
            c0 = fmaf(Tt, v.x, c0);
            c1 = fmaf(Tt, v.y, c1);
            c2 = fmaf(Tt, v.z, c2);
            Tt *= v.w;
        }
        int pix = (ty * TILE + (tid >> 3)) * WW + tx * TILE + (tid & 7);
        out[pix]            = c0 + Tt * bg[0];
        out[NPIX + pix]     = c1 + Tt * bg[1];
        out[2 * NPIX + pix] = c2 + Tt * bg[2];
    }
}

extern "C" void kernel_launch(void* const* d_in, const int* in_sizes, int n_in,
                              void* d_out, int out_size, void* d_ws, size_t ws_size,
                              hipStream_t stream) {
    const float* means  = (const float*)d_in[0];
    const float* cols   = (const float*)d_in[2];
    const float* ops    = (const float*)d_in[3];
    const float* scales = (const float*)d_in[4];
    const float* rots   = (const float*)d_in[5];
    const float* bg     = (const float*)d_in[6];
    const float* vm     = (const float*)d_in[7];
    const float* pm     = (const float*)d_in[8];

    float* out = (float*)d_out;   // [3*NPIX color][PCNT radii-as-float]

    k_all<<<NTILES, 256, 0, stream>>>(means, cols, ops, scales, rots, vm, pm, bg, out);
}

// Round 8
// 17.644 us; speedup vs baseline: 6.6368x; 1.2993x over previous
//
#include <hip/hip_runtime.h>
#include <math.h>

#define PCNT 1024
#define HH 160
#define WW 160
#define NPIX (HH * WW)
#define TILE 8
#define TX (WW / TILE)       // 20
#define TY (HH / TILE)       // 20
#define NTILES (TX * TY)     // 400

// One block = one 8x8 tile. The block recomputes preprocess for ALL gaussians
// into LDS (redundant across blocks, but removes every cross-block dependency:
// single dispatch, no grid sync, no global scratch).
__global__ __launch_bounds__(256) void k_all(
    const float* __restrict__ means, const float* __restrict__ cols,
    const float* __restrict__ ops, const float* __restrict__ scales,
    const float* __restrict__ rots, const float* __restrict__ vm,
    const float* __restrict__ pm, const float* __restrict__ bg,
    float* __restrict__ out)
{
    __shared__ float4 sp[PCNT * 3];           // 48 KB params {px,py,ca',cb'},{cc',op,r,g},{b,-,-,-}
    __shared__ float4 cl[PCNT];               // 16 KB cull {px,py,hx,hy}; reused as part[] later
    __shared__ unsigned int kbits[PCNT];      // 4 KB depth key bits; reused as ranked[] later
    __shared__ unsigned long long sl[PCNT];   // 8 KB per-tile compacted key list
    __shared__ unsigned long long masks[16];  // per-chunk overlap ballots
    __shared__ int offs[16];
    __shared__ int sn;

    int tid = threadIdx.x;
    int bid = blockIdx.x;
    int wave = tid >> 6, lane = tid & 63;

    const float HL2E = 0.72134752044448170f;  // 0.5*log2(e)
    const float L2E  = 1.4426950408889634f;   // log2(e)

    // ---------------- Phase A: preprocess all gaussians into LDS ----------------
    for (int i = tid; i < PCNT; i += 256) {
        float mx = means[3 * i], my = means[3 * i + 1], mz = means[3 * i + 2];

        float t0 = vm[0] * mx + vm[1] * my + vm[2] * mz + vm[3];
        float t1 = vm[4] * mx + vm[5] * my + vm[6] * mz + vm[7];
        float t2 = vm[8] * mx + vm[9] * my + vm[10] * mz + vm[11];
        bool depth_ok = t2 > 0.2f;

        float ph0 = pm[0] * mx + pm[1] * my + pm[2] * mz + pm[3];
        float ph1 = pm[4] * mx + pm[5] * my + pm[6] * mz + pm[7];
        float ph3 = pm[12] * mx + pm[13] * my + pm[14] * mz + pm[15];
        float pw = 1.0f / (ph3 + 1e-7f);
        float px = ((ph0 * pw + 1.0f) * (float)WW - 1.0f) * 0.5f;
        float py = ((ph1 * pw + 1.0f) * (float)HH - 1.0f) * 0.5f;

        float qr = rots[4 * i], qx = rots[4 * i + 1], qy = rots[4 * i + 2], qz = rots[4 * i + 3];
        float R00 = 1.f - 2.f * (qy * qy + qz * qz), R01 = 2.f * (qx * qy - qr * qz), R02 = 2.f * (qx * qz + qr * qy);
        float R10 = 2.f * (qx * qy + qr * qz), R11 = 1.f - 2.f * (qx * qx + qz * qz), R12 = 2.f * (qy * qz - qr * qx);
        float R20 = 2.f * (qx * qz - qr * qy), R21 = 2.f * (qy * qz + qr * qx), R22 = 1.f - 2.f * (qx * qx + qy * qy);

        float s0 = scales[3 * i], s1 = scales[3 * i + 1], s2 = scales[3 * i + 2];
        float M00 = R00 * s0, M01 = R01 * s1, M02 = R02 * s2;
        float M10 = R10 * s0, M11 = R11 * s1, M12 = R12 * s2;
        float M20 = R20 * s0, M21 = R21 * s1, M22 = R22 * s2;
        float c00 = M00 * M00 + M01 * M01 + M02 * M02;
        float c01 = M00 * M10 + M01 * M11 + M02 * M12;
        float c02 = M00 * M20 + M01 * M21 + M02 * M22;
        float c11 = M10 * M10 + M11 * M11 + M12 * M12;
        float c12 = M10 * M20 + M11 * M21 + M12 * M22;
        float c22 = M20 * M20 + M21 * M21 + M22 * M22;

        const float fx = 160.0f, fy = 160.0f;
        const float limx = 0.65f, limy = 0.65f;
        float txz = fminf(limx, fmaxf(-limx, t0 / t2)) * t2;
        float tyz = fminf(limy, fmaxf(-limy, t1 / t2)) * t2;
        float J00 = fx / t2, J02 = -fx * txz / (t2 * t2);
        float J11 = fy / t2, J12 = -fy * tyz / (t2 * t2);

        float T00 = J00 * vm[0] + J02 * vm[8];
        float T01 = J00 * vm[1] + J02 * vm[9];
        float T02 = J00 * vm[2] + J02 * vm[10];
        float T10 = J11 * vm[4] + J12 * vm[8];
        float T11 = J11 * vm[5] + J12 * vm[9];
        float T12 = J11 * vm[6] + J12 * vm[10];

        float u00 = T00 * c00 + T01 * c01 + T02 * c02;
        float u01 = T00 * c01 + T01 * c11 + T02 * c12;
        float u02 = T00 * c02 + T01 * c12 + T02 * c22;
        float u10 = T10 * c00 + T11 * c01 + T12 * c02;
        float u11 = T10 * c01 + T11 * c11 + T12 * c12;
        float u12 = T10 * c02 + T11 * c12 + T12 * c22;
        float a  = u00 * T00 + u01 * T01 + u02 * T02 + 0.3f;
        float bb = u00 * T10 + u01 * T11 + u02 * T12;
        float cc = u10 * T10 + u11 * T11 + u12 * T12 + 0.3f;

        float det = a * cc - bb * bb;
        bool det_ok = det > 0.0f;
        float inv_det = det_ok ? 1.0f / det : 0.0f;
        float conA = cc * inv_det, conB = -bb * inv_det, conC = a * inv_det;
        float mid = 0.5f * (a + cc);
        float lam1 = mid + sqrtf(fmaxf(0.1f, mid * mid - det));
        float radius = ceilf(3.0f * sqrtf(lam1));
        bool valid = depth_ok && det_ok;

        if (bid == 0)
            out[3 * NPIX + i] = valid ? (float)(int)radius : 0.0f;

        if (valid) {
            float op = ops[i];
            // contribution exactly 0 unless Q <= tau (alpha >= 1/255);
            // bounding half-widths: hx=sqrt(2*tau*a), hy=sqrt(2*tau*c) (+slop).
            float tau = fmaxf(logf(255.0f * op) + 0.02f, 0.0f);
            float hx = sqrtf(2.0f * tau * a);
            float hy = sqrtf(2.0f * tau * cc);
            sp[i * 3 + 0] = make_float4(px, py, conA * HL2E, conB * L2E);
            sp[i * 3 + 1] = make_float4(conC * HL2E, op, cols[3 * i], cols[3 * i + 1]);
            sp[i * 3 + 2] = make_float4(cols[3 * i + 2], 0.f, 0.f, 0.f);
            cl[i] = make_float4(px, py, hx, hy);
            kbits[i] = __float_as_uint(t2);
        } else {
            sp[i * 3 + 0] = make_float4(0.f, 0.f, 0.f, 0.f);
            sp[i * 3 + 1] = make_float4(0.f, 0.f, 0.f, 0.f);
            sp[i * 3 + 2] = make_float4(0.f, 0.f, 0.f, 0.f);
            cl[i] = make_float4(0.f, 0.f, -1e9f, -1e9f);  // never overlaps
            kbits[i] = 0x7f800000u;
        }
    }
    __syncthreads();

    // ---------------- Phase B: tile cull + ordered compaction (all waves) ----------------
    int tx = bid % TX, ty = bid / TX;
    float x0 = (float)(tx * TILE), y0 = (float)(ty * TILE);

    #pragma unroll
    for (int k = 0; k < 4; ++k) {
        int c = wave * 4 + k;
        float4 cv = cl[c * 64 + lane];
        bool ov = (cv.x + cv.z >= x0 - 1.0f) & (cv.x - cv.z <= x0 + (float)TILE) &
                  (cv.y + cv.w >= y0 - 1.0f) & (cv.y - cv.w <= y0 + (float)TILE);
        unsigned long long m = __ballot(ov);
        if (lane == 0) masks[c] = m;
    }
    __syncthreads();
    if (tid == 0) {
        int acc = 0;
        #pragma unroll
        for (int c = 0; c < 16; ++c) { offs[c] = acc; acc += __popcll(masks[c]); }
        sn = acc;
    }
    __syncthreads();
    #pragma unroll
    for (int k = 0; k < 4; ++k) {
        int c = wave * 4 + k;
        unsigned long long m = masks[c];
        if ((m >> lane) & 1ull) {
            int g = c * 64 + lane;
            int pos = offs[c] + __popcll(m & ((1ull << lane) - 1ull));
            sl[pos] = ((unsigned long long)kbits[g] << 32) | (unsigned int)g;
        }
    }
    __syncthreads();
    int n = sn;

    // ---------------- Phase C: rank-by-count ordering (keys unique) ----------------
    unsigned short* ranked = (unsigned short*)kbits;   // kbits dead after Phase B
    for (int t = tid; t < n; t += 256) {
        unsigned long long key = sl[t];
        int cnt = 0, k = 0;
        for (; k + 4 <= n; k += 4) {
            cnt += (sl[k]     < key) ? 1 : 0;
            cnt += (sl[k + 1] < key) ? 1 : 0;
            cnt += (sl[k + 2] < key) ? 1 : 0;
            cnt += (sl[k + 3] < key) ? 1 : 0;
        }
        for (; k < n; ++k) cnt += (sl[k] < key) ? 1 : 0;
        ranked[cnt] = (unsigned short)(key & 1023u);
    }
    __syncthreads();

    // ---------------- Phase D: segmented front-to-back composite ----------------
    float fxp = x0 + (float)(lane & 7);
    float fyp = y0 + (float)(lane >> 3);

    float T = 1.0f, C0 = 0.f, C1 = 0.f, C2 = 0.f;
    int per = (n + 3) >> 2;
    int lo = wave * per, hi = min(n, lo + per);
    for (int i = lo; i < hi; ++i) {
        int id = ranked[i];
        float4 v0 = sp[id * 3 + 0];   // px,py,ca',cb'
        float4 v1 = sp[id * 3 + 1];   // cc',op,r,g
        float4 v2 = sp[id * 3 + 2];   // b,-,-,-
        float dx = v0.x - fxp, dy = v0.y - fyp;
        float p = -(v0.z * dx * dx + v1.x * dy * dy) - v0.w * dx * dy;
        float e; asm("v_exp_f32 %0, %1" : "=v"(e) : "v"(p));
        float al = fminf(0.99f, v1.y * e);
        if (p > 0.0f || al < (1.0f / 255.0f)) al = 0.0f;
        float w = al * T;
        C0 = fmaf(w, v1.z, C0);
        C1 = fmaf(w, v1.w, C1);
        C2 = fmaf(w, v2.x, C2);
        T *= (1.0f - al);
    }

    // reuse cl[] as the partials buffer (cull data dead after Phase B)
    float4* part = cl;
    __syncthreads();
    part[wave * 64 + lane] = make_float4(C0, C1, C2, T);
    __syncthreads();

    if (tid < 64) {
        float Tt = 1.0f, c0 = 0.f, c1 = 0.f, c2 = 0.f;
        #pragma unroll
        for (int s = 0; s < 4; ++s) {
            float4 v = part[s * 64 + tid];
            c0 = fmaf(Tt, v.x, c0);
            c1 = fmaf(Tt, v.y, c1);
            c2 = fmaf(Tt, v.z, c2);
            Tt *= v.w;
        }
        int pix = (ty * TILE + (tid >> 3)) * WW + tx * TILE + (tid & 7);
        out[pix]            = c0 + Tt * bg[0];
        out[NPIX + pix]     = c1 + Tt * bg[1];
        out[2 * NPIX + pix] = c2 + Tt * bg[2];
    }
}

extern "C" void kernel_launch(void* const* d_in, const int* in_sizes, int n_in,
                              void* d_out, int out_size, void* d_ws, size_t ws_size,
                              hipStream_t stream) {
    const float* means  = (const float*)d_in[0];
    const float* cols   = (const float*)d_in[2];
    const float* ops    = (const float*)d_in[3];
    const float* scales = (const float*)d_in[4];
    const float* rots   = (const float*)d_in[5];
    const float* bg     = (const float*)d_in[6];
    const float* vm     = (const float*)d_in[7];
    const float* pm     = (const float*)d_in[8];

    float* out = (float*)d_out;   // [3*NPIX color][PCNT radii-as-float]

    k_all<<<NTILES, 256, 0, stream>>>(means, cols, ops, scales, rots, vm, pm, bg, out);
}